// Round 1
// baseline (237.356 us; speedup 1.0000x reference)
//
#include <hip/hip_runtime.h>
#include <hip/hip_bf16.h>

// out[256, 100000] = (inputs[256,256] @ features[100000,256]^T) / 0.07
//
// v2 vs v1 (v1: kernel 73 us, Occ 33%, MfmaUtil 6.5%, HBM 26%):
//  1. GRID 256->512 + __launch_bounds__(1024,8): 2 blocks/CU (32 waves/CU).
//     One block's barrier stalls overlap the other block's compute/stores.
//  2. __syncthreads() -> lgkmcnt(0)-only raw s_barrier. HIP __syncthreads
//     drains vmcnt(0) at every barrier, serializing the in-flight output
//     stores + prefetch loads each tile. LDS ordering only needs lgkmcnt;
//     the prefetch f32 registers get a counted vmcnt wait at their staging
//     consumption (compiler-inserted), and stores retire lazily.
//  3. MFMA operand swap: acc = mfma(feat_frag, input_frag). A/B fragment
//     lane layouts are symmetric (row/col = l16, k = quad*8+j), so register
//     contents are unchanged; the D fragment now holds 4 CONSECUTIVE n per
//     lane at fixed m -> one float4 nontemporal store per n-subtile
//     (16 -> 4 store instrs per wave per tile), out is write-once so `nt`
//     avoids evicting L3-resident features.

typedef __attribute__((ext_vector_type(8))) __bf16 bf16x8;   // 4 VGPRs
typedef __attribute__((ext_vector_type(4))) float  floatx4;  // MFMA acc
typedef __attribute__((ext_vector_type(4))) unsigned int uint4v;

#define NB 100000
#define KD 256
#define BN 64
#define NTILES 1563           // ceil(NB / BN)
#define GRID 512              // 2 persistent blocks per CU
#define LDS_STRIDE 132        // dwords/row: 128 data + 4 pad

union FragCast { uint4v u; bf16x8 f; };

__device__ __forceinline__ unsigned pk(float a, float b) {
  // v_cvt_pk_bf16_f32 (RNE)
  __hip_bfloat162 h = __float22bfloat162_rn(float2{a, b});
  union { __hip_bfloat162 h2; unsigned u; } c; c.h2 = h; return c.u;
}

// Workgroup barrier with lgkmcnt(0) only -- no vmcnt(0) drain.
// Safe: all cross-wave hazards here are LDS (lgkm); global stores have no
// reader, and prefetch-load RAW is enforced by the compiler's counted vmcnt
// at the point the pf registers are consumed.
__device__ __forceinline__ void barrier_lgkm() {
  asm volatile("s_waitcnt lgkmcnt(0)" ::: "memory");
  __builtin_amdgcn_s_barrier();
  asm volatile("" ::: "memory");
}

__global__ __launch_bounds__(1024, 8)
void sct_gemm(const float* __restrict__ inputs,
              const float* __restrict__ features,
              float* __restrict__ out) {
  __shared__ unsigned lds[BN * LDS_STRIDE];   // 33792 B bf16 B-tile

  const int tid  = threadIdx.x;
  const int ws   = tid >> 6;     // wave 0..15 -> m-subtile
  const int lane = tid & 63;
  const int quad = lane >> 4;
  const int l16  = lane & 15;
  const int q4   = quad * 4;

  const int b = blockIdx.x;
  const int ntiles = (NTILES - b + GRID - 1) / GRID;

  // staging decomposition: chunk c = i*1024 + tid; row r = c>>5, 8-float
  // chunk ck = c&31 within the row (coalesced across consecutive tid).
  const int srow0 = tid >> 5,     sck0 = tid & 31;
  const int srow1 = 32 + srow0,   sck1 = sck0;

  // ---- prefetch tile 0 into registers ----
  float4 pf0a, pf0b, pf1a, pf1b;
  {
    const int n0 = b * BN;
    pf0a = pf0b = pf1a = pf1b = make_float4(0.f, 0.f, 0.f, 0.f);
    if (n0 + srow0 < NB) {
      const float4* p = (const float4*)(features + (size_t)(n0 + srow0) * KD + sck0 * 8);
      pf0a = p[0]; pf0b = p[1];
    }
    if (n0 + srow1 < NB) {
      const float4* p = (const float4*)(features + (size_t)(n0 + srow1) * KD + sck1 * 8);
      pf1a = p[0]; pf1b = p[1];
    }
  }

  // ---- A fragments (once per block), scale folded in ----
  const float scale = 1.0f / 0.07f;
  bf16x8 afrag[8];                         // 32 VGPRs
  {
    const float* arow = inputs + (ws * 16 + l16) * KD + quad * 8;
    #pragma unroll
    for (int t = 0; t < 8; ++t) {
      const float4* p = (const float4*)(arow + t * 32);
      const float4 a0 = p[0], a1 = p[1];
      FragCast fc;
      fc.u.x = pk(a0.x * scale, a0.y * scale);
      fc.u.y = pk(a0.z * scale, a0.w * scale);
      fc.u.z = pk(a1.x * scale, a1.y * scale);
      fc.u.w = pk(a1.z * scale, a1.w * scale);
      afrag[t] = fc.f;
    }
  }

  // lane's output row: m = ws*16 + l16 (operand-swapped D: col = l16 = m,
  // row = quad*4 + reg = n within the 16-wide n-subtile)
  float* const orow = out + (size_t)(ws * 16 + l16) * NB;

  for (int it = 0; it < ntiles; ++it) {
    const int n0 = (b + it * GRID) * BN;

    barrier_lgkm();   // all waves' LDS reads of previous tile retired

    // ---- stage current tile: convert prefetched f32 -> bf16 -> LDS ----
    {
      uint4v w;
      w.x = pk(pf0a.x, pf0a.y); w.y = pk(pf0a.z, pf0a.w);
      w.z = pk(pf0b.x, pf0b.y); w.w = pk(pf0b.z, pf0b.w);
      *(uint4v*)&lds[srow0 * LDS_STRIDE + sck0 * 4] = w;
      w.x = pk(pf1a.x, pf1a.y); w.y = pk(pf1a.z, pf1a.w);
      w.z = pk(pf1b.x, pf1b.y); w.w = pk(pf1b.z, pf1b.w);
      *(uint4v*)&lds[srow1 * LDS_STRIDE + sck1 * 4] = w;
    }

    barrier_lgkm();   // staged tile visible to all waves

    // ---- issue prefetch for next tile (consumed next iteration) ----
    if (it + 1 < ntiles) {
      const int nn0 = (b + (it + 1) * GRID) * BN;
      pf0a = pf0b = pf1a = pf1b = make_float4(0.f, 0.f, 0.f, 0.f);
      if (nn0 + srow0 < NB) {
        const float4* p = (const float4*)(features + (size_t)(nn0 + srow0) * KD + sck0 * 8);
        pf0a = p[0]; pf0b = p[1];
      }
      if (nn0 + srow1 < NB) {
        const float4* p = (const float4*)(features + (size_t)(nn0 + srow1) * KD + sck1 * 8);
        pf1a = p[0]; pf1b = p[1];
      }
    }

    // ---- MFMA (operand-swapped): 4 n-subtiles, K=256 in 8 steps ----
    floatx4 acc[4];
    #pragma unroll
    for (int nt = 0; nt < 4; ++nt) acc[nt] = floatx4{0.f, 0.f, 0.f, 0.f};

    #pragma unroll
    for (int t = 0; t < 8; ++t) {
      #pragma unroll
      for (int nt = 0; nt < 4; ++nt) {
        FragCast fc;
        fc.u = *(const uint4v*)&lds[(nt * 16 + l16) * LDS_STRIDE + t * 16 + q4];
        acc[nt] = __builtin_amdgcn_mfma_f32_16x16x32_bf16(fc.f, afrag[t], acc[nt], 0, 0, 0);
      }
    }

    // ---- store: one float4 (4 consecutive n) per n-subtile, nontemporal ----
    #pragma unroll
    for (int nt = 0; nt < 4; ++nt) {
      const int n = n0 + nt * 16 + q4;
      if (n < NB)    // NB%4==0 so the float4 is all-in or all-out
        __builtin_nontemporal_store(acc[nt], (floatx4*)(orow + n));
    }
  }
}

extern "C" void kernel_launch(void* const* d_in, const int* in_sizes, int n_in,
                              void* d_out, int out_size, void* d_ws, size_t ws_size,
                              hipStream_t stream) {
  const float* inputs   = (const float*)d_in[0];  // [256,256] f32
  // d_in[1] = indexes (unused), d_in[3] = momentum (unused)
  const float* features = (const float*)d_in[2];  // [100000,256] f32
  float* out = (float*)d_out;                     // [256,100000] f32

  sct_gemm<<<GRID, 1024, 0, stream>>>(inputs, features, out);
}

// Round 2
// 210.086 us; speedup vs baseline: 1.1298x; 1.1298x over previous
//
#include <hip/hip_runtime.h>
#include <hip/hip_bf16.h>

// out[256, 100000] = (inputs[256,256] @ features[100000,256]^T) / 0.07
//
// v3 vs v2 (v2: 111 us, Occ 65%, VGPR 32, WRITE 172MB <- SPILLS):
//  1. __launch_bounds__(1024, 8) -> (1024, 4). The 8-waves/EU bound forced
//     VGPR 48->32 (< ~64-reg demand) and the allocator spilled to scratch:
//     +70MB writes / +42MB fetches per launch. v1 compiled to 48 VGPR
//     (+16 acc) under (1024,4), which ALREADY fits 8 waves/SIMD; occupancy
//     was grid-limited, not register-limited. GRID=512 stays -> 2 blocks/CU
//     with no forced register cap.
//  2. LDS_STRIDE 132 -> 136. At 132 the odd staging rows start bank-quad
//     unaligned (+1 dword), so the b128 staging writes take extra bank
//     passes (SQ_LDS_BANK_CONFLICT 3.2M/dispatch). At 136 both the write
//     pattern (banks 4*(2*srow+sck) mod 32, quad-aligned) and the MFMA
//     read pattern are minimal 8-pass. LDS 34816 B/block; 2 blocks = 69.6KB.
//  Kept from v2: operand-swapped MFMA (acc = mfma(feat, input), D holds 4
//  consecutive n per lane -> single float4 nontemporal store per subtile),
//  lgkmcnt-only barrier (no vmcnt(0) drain of stores/prefetch each tile),
//  register prefetch of the next features tile across the barrier.

typedef __attribute__((ext_vector_type(8))) __bf16 bf16x8;   // 4 VGPRs
typedef __attribute__((ext_vector_type(4))) float  floatx4;  // MFMA acc
typedef __attribute__((ext_vector_type(4))) unsigned int uint4v;

#define NB 100000
#define KD 256
#define BN 64
#define NTILES 1563           // ceil(NB / BN)
#define GRID 512              // 2 persistent blocks per CU
#define LDS_STRIDE 136        // dwords/row: 128 data + 8 pad (bank-quad aligned)

union FragCast { uint4v u; bf16x8 f; };

__device__ __forceinline__ unsigned pk(float a, float b) {
  // v_cvt_pk_bf16_f32 (RNE)
  __hip_bfloat162 h = __float22bfloat162_rn(float2{a, b});
  union { __hip_bfloat162 h2; unsigned u; } c; c.h2 = h; return c.u;
}

// Workgroup barrier with lgkmcnt(0) only -- no vmcnt(0) drain.
// Safe: all cross-wave hazards here are LDS (lgkm); global stores have no
// reader, and prefetch-load RAW is enforced by the compiler's counted vmcnt
// at the point the pf registers are consumed.
__device__ __forceinline__ void barrier_lgkm() {
  asm volatile("s_waitcnt lgkmcnt(0)" ::: "memory");
  __builtin_amdgcn_s_barrier();
  asm volatile("" ::: "memory");
}

__global__ __launch_bounds__(1024, 4)
void sct_gemm(const float* __restrict__ inputs,
              const float* __restrict__ features,
              float* __restrict__ out) {
  __shared__ unsigned lds[BN * LDS_STRIDE];   // 34816 B bf16 B-tile

  const int tid  = threadIdx.x;
  const int ws   = tid >> 6;     // wave 0..15 -> m-subtile
  const int lane = tid & 63;
  const int quad = lane >> 4;
  const int l16  = lane & 15;
  const int q4   = quad * 4;

  const int b = blockIdx.x;
  const int ntiles = (NTILES - b + GRID - 1) / GRID;

  // staging decomposition: chunk c = i*1024 + tid; row r = c>>5, 8-float
  // chunk ck = c&31 within the row (coalesced across consecutive tid).
  const int srow0 = tid >> 5,     sck0 = tid & 31;
  const int srow1 = 32 + srow0,   sck1 = sck0;

  // ---- prefetch tile 0 into registers ----
  float4 pf0a, pf0b, pf1a, pf1b;
  {
    const int n0 = b * BN;
    pf0a = pf0b = pf1a = pf1b = make_float4(0.f, 0.f, 0.f, 0.f);
    if (n0 + srow0 < NB) {
      const float4* p = (const float4*)(features + (size_t)(n0 + srow0) * KD + sck0 * 8);
      pf0a = p[0]; pf0b = p[1];
    }
    if (n0 + srow1 < NB) {
      const float4* p = (const float4*)(features + (size_t)(n0 + srow1) * KD + sck1 * 8);
      pf1a = p[0]; pf1b = p[1];
    }
  }

  // ---- A fragments (once per block), scale folded in ----
  const float scale = 1.0f / 0.07f;
  bf16x8 afrag[8];                         // 32 VGPRs
  {
    const float* arow = inputs + (ws * 16 + l16) * KD + quad * 8;
    #pragma unroll
    for (int t = 0; t < 8; ++t) {
      const float4* p = (const float4*)(arow + t * 32);
      const float4 a0 = p[0], a1 = p[1];
      FragCast fc;
      fc.u.x = pk(a0.x * scale, a0.y * scale);
      fc.u.y = pk(a0.z * scale, a0.w * scale);
      fc.u.z = pk(a1.x * scale, a1.y * scale);
      fc.u.w = pk(a1.z * scale, a1.w * scale);
      afrag[t] = fc.f;
    }
  }

  // lane's output row: m = ws*16 + l16 (operand-swapped D: col = l16 = m,
  // row = quad*4 + reg = n within the 16-wide n-subtile)
  float* const orow = out + (size_t)(ws * 16 + l16) * NB;

  for (int it = 0; it < ntiles; ++it) {
    const int n0 = (b + it * GRID) * BN;

    barrier_lgkm();   // all waves' LDS reads of previous tile retired

    // ---- stage current tile: convert prefetched f32 -> bf16 -> LDS ----
    {
      uint4v w;
      w.x = pk(pf0a.x, pf0a.y); w.y = pk(pf0a.z, pf0a.w);
      w.z = pk(pf0b.x, pf0b.y); w.w = pk(pf0b.z, pf0b.w);
      *(uint4v*)&lds[srow0 * LDS_STRIDE + sck0 * 4] = w;
      w.x = pk(pf1a.x, pf1a.y); w.y = pk(pf1a.z, pf1a.w);
      w.z = pk(pf1b.x, pf1b.y); w.w = pk(pf1b.z, pf1b.w);
      *(uint4v*)&lds[srow1 * LDS_STRIDE + sck1 * 4] = w;
    }

    barrier_lgkm();   // staged tile visible to all waves

    // ---- issue prefetch for next tile (consumed next iteration) ----
    if (it + 1 < ntiles) {
      const int nn0 = (b + (it + 1) * GRID) * BN;
      pf0a = pf0b = pf1a = pf1b = make_float4(0.f, 0.f, 0.f, 0.f);
      if (nn0 + srow0 < NB) {
        const float4* p = (const float4*)(features + (size_t)(nn0 + srow0) * KD + sck0 * 8);
        pf0a = p[0]; pf0b = p[1];
      }
      if (nn0 + srow1 < NB) {
        const float4* p = (const float4*)(features + (size_t)(nn0 + srow1) * KD + sck1 * 8);
        pf1a = p[0]; pf1b = p[1];
      }
    }

    // ---- MFMA (operand-swapped): 4 n-subtiles, K=256 in 8 steps ----
    floatx4 acc[4];
    #pragma unroll
    for (int nt = 0; nt < 4; ++nt) acc[nt] = floatx4{0.f, 0.f, 0.f, 0.f};

    #pragma unroll
    for (int t = 0; t < 8; ++t) {
      #pragma unroll
      for (int nt = 0; nt < 4; ++nt) {
        FragCast fc;
        fc.u = *(const uint4v*)&lds[(nt * 16 + l16) * LDS_STRIDE + t * 16 + q4];
        acc[nt] = __builtin_amdgcn_mfma_f32_16x16x32_bf16(fc.f, afrag[t], acc[nt], 0, 0, 0);
      }
    }

    // ---- store: one float4 (4 consecutive n) per n-subtile, nontemporal ----
    #pragma unroll
    for (int nt = 0; nt < 4; ++nt) {
      const int n = n0 + nt * 16 + q4;
      if (n < NB)    // NB%4==0 so the float4 is all-in or all-out
        __builtin_nontemporal_store(acc[nt], (floatx4*)(orow + n));
    }
  }
}

extern "C" void kernel_launch(void* const* d_in, const int* in_sizes, int n_in,
                              void* d_out, int out_size, void* d_ws, size_t ws_size,
                              hipStream_t stream) {
  const float* inputs   = (const float*)d_in[0];  // [256,256] f32
  // d_in[1] = indexes (unused), d_in[3] = momentum (unused)
  const float* features = (const float*)d_in[2];  // [100000,256] f32
  float* out = (float*)d_out;                     // [256,100000] f32

  sct_gemm<<<GRID, 1024, 0, stream>>>(inputs, features, out);
}

// Round 3
// 199.056 us; speedup vs baseline: 1.1924x; 1.0554x over previous
//
#include <hip/hip_runtime.h>
#include <hip/hip_bf16.h>

// out[256, 100000] = (inputs[256,256] @ features[100000,256]^T) / 0.07
//
// v4 vs v3 (v3: 82 us/dispatch, Occ 35%, WRITE 141MB, LDS-conflicts 0):
//  1. Revert nontemporal stores -> plain float4 stores. nt bypassed L2
//     write-combining of the 64B half-line segments: WRITE_SIZE 101->141MB
//     (+40%), which was the whole v3 regression. Plain stores measured
//     exactly 101MB in v1.
//  2. Drop the 2-blocks/CU attempt (GRID 512->256). v3 proved it doesn't
//     co-schedule at ~80 total regs/wave; occupancy is not the lever.
//  3. LDS double-buffer + ONE lgkm barrier per iteration (was 2). Iter it:
//     barrier -> stage tile it+1 into buf[nb] (other waves simultaneously
//     MFMA from buf[cb]; different buffer, WAR ordered by the loop-top
//     barrier) -> issue prefetch of tile it+2 -> MFMA -> stores. The pf
//     vmcnt wait + ds_writes now overlap the block's own MFMA phase.
//  4. Pad-136 -> chunk-XOR swizzle at stride 128 (chunk ^= row&7, 16B
//     chunks) so both buffers fit in exactly 64KB static LDS. Write side:
//     32 distinct chunks per 32-lane group (conflict-free). Read side:
//     8 lanes per bank-quad = structural minimum. Both sides swizzled
//     (reg-staged, no global_load_lds) per rule #21.

typedef __attribute__((ext_vector_type(8))) __bf16 bf16x8;   // 4 VGPRs
typedef __attribute__((ext_vector_type(4))) float  floatx4;  // MFMA acc
typedef __attribute__((ext_vector_type(4))) unsigned int uint4v;

#define NB 100000
#define KD 256
#define BN 64
#define NTILES 1563           // ceil(NB / BN)
#define GRID 256              // 1 persistent block per CU
#define NCHUNK 32             // 16B chunks per 64-row: 128 dwords, no pad

union FragCast { uint4v u; bf16x8 f; };

__device__ __forceinline__ unsigned pk(float a, float b) {
  // v_cvt_pk_bf16_f32 (RNE)
  __hip_bfloat162 h = __float22bfloat162_rn(float2{a, b});
  union { __hip_bfloat162 h2; unsigned u; } c; c.h2 = h; return c.u;
}

// Workgroup barrier with lgkmcnt(0) only -- no vmcnt(0) drain.
// All cross-wave hazards are LDS (lgkm); global stores have no reader and
// retire lazily; prefetch-load RAW is enforced by the compiler's counted
// vmcnt at the point the pf registers are consumed.
__device__ __forceinline__ void barrier_lgkm() {
  asm volatile("s_waitcnt lgkmcnt(0)" ::: "memory");
  __builtin_amdgcn_s_barrier();
  asm volatile("" ::: "memory");
}

__global__ __launch_bounds__(1024, 4)
void sct_gemm(const float* __restrict__ inputs,
              const float* __restrict__ features,
              float* __restrict__ out) {
  // double-buffered bf16 B-tile, chunk-swizzled: 2*64*32*16B = 65536 B
  __shared__ uint4v lds[2][BN][NCHUNK];

  const int tid  = threadIdx.x;
  const int ws   = tid >> 6;     // wave 0..15 -> m-subtile
  const int lane = tid & 63;
  const int quad = lane >> 4;
  const int l16  = lane & 15;
  const int q4   = quad * 4;
  const int e3   = l16 & 7;      // read-side swizzle key

  const int b = blockIdx.x;
  const int ntiles = (NTILES - b + GRID - 1) / GRID;

  // staging decomposition: thread stages chunk sck of rows srow0, srow0+32
  const int srow0 = tid >> 5, sck = tid & 31;
  const int srow1 = 32 + srow0;
  const int wch0 = sck ^ (srow0 & 7);   // swizzled write chunks
  const int wch1 = sck ^ (srow1 & 7);

  // ---- prefetch tile 0 into registers ----
  float4 pf0a, pf0b, pf1a, pf1b;
  {
    const int n0 = b * BN;
    pf0a = pf0b = pf1a = pf1b = make_float4(0.f, 0.f, 0.f, 0.f);
    if (n0 + srow0 < NB) {
      const float4* p = (const float4*)(features + (size_t)(n0 + srow0) * KD + sck * 8);
      pf0a = p[0]; pf0b = p[1];
    }
    if (n0 + srow1 < NB) {
      const float4* p = (const float4*)(features + (size_t)(n0 + srow1) * KD + sck * 8);
      pf1a = p[0]; pf1b = p[1];
    }
  }

  // ---- A fragments (once per block), scale folded in ----
  const float scale = 1.0f / 0.07f;
  bf16x8 afrag[8];                         // 32 VGPRs
  {
    const float* arow = inputs + (ws * 16 + l16) * KD + quad * 8;
    #pragma unroll
    for (int t = 0; t < 8; ++t) {
      const float4* p = (const float4*)(arow + t * 32);
      const float4 a0 = p[0], a1 = p[1];
      FragCast fc;
      fc.u.x = pk(a0.x * scale, a0.y * scale);
      fc.u.y = pk(a0.z * scale, a0.w * scale);
      fc.u.z = pk(a1.x * scale, a1.y * scale);
      fc.u.w = pk(a1.z * scale, a1.w * scale);
      afrag[t] = fc.f;
    }
  }

  // ---- prologue: stage tile 0 into buf0, then prefetch tile 1 ----
  {
    uint4v w;
    w.x = pk(pf0a.x, pf0a.y); w.y = pk(pf0a.z, pf0a.w);
    w.z = pk(pf0b.x, pf0b.y); w.w = pk(pf0b.z, pf0b.w);
    lds[0][srow0][wch0] = w;
    w.x = pk(pf1a.x, pf1a.y); w.y = pk(pf1a.z, pf1a.w);
    w.z = pk(pf1b.x, pf1b.y); w.w = pk(pf1b.z, pf1b.w);
    lds[0][srow1][wch1] = w;
  }
  if (1 < ntiles) {
    const int nn0 = (b + GRID) * BN;
    pf0a = pf0b = pf1a = pf1b = make_float4(0.f, 0.f, 0.f, 0.f);
    if (nn0 + srow0 < NB) {
      const float4* p = (const float4*)(features + (size_t)(nn0 + srow0) * KD + sck * 8);
      pf0a = p[0]; pf0b = p[1];
    }
    if (nn0 + srow1 < NB) {
      const float4* p = (const float4*)(features + (size_t)(nn0 + srow1) * KD + sck * 8);
      pf1a = p[0]; pf1b = p[1];
    }
  }

  // lane's output row: m = ws*16 + l16 (operand-swapped D: 4 consecutive n
  // per lane at fixed m)
  float* const orow = out + (size_t)(ws * 16 + l16) * NB;

  for (int it = 0; it < ntiles; ++it) {
    const int n0 = (b + it * GRID) * BN;
    const int cb = it & 1, nb = cb ^ 1;

    // orders: prev-iter reads of buf[nb] BEFORE this iter's writes to it,
    // and prev-iter writes of buf[cb] BEFORE this iter's reads of it.
    barrier_lgkm();

    // ---- stage tile it+1 into buf[nb] (overlaps other waves' MFMA) ----
    if (it + 1 < ntiles) {
      uint4v w;
      w.x = pk(pf0a.x, pf0a.y); w.y = pk(pf0a.z, pf0a.w);
      w.z = pk(pf0b.x, pf0b.y); w.w = pk(pf0b.z, pf0b.w);
      lds[nb][srow0][wch0] = w;
      w.x = pk(pf1a.x, pf1a.y); w.y = pk(pf1a.z, pf1a.w);
      w.z = pk(pf1b.x, pf1b.y); w.w = pk(pf1b.z, pf1b.w);
      lds[nb][srow1][wch1] = w;
    }

    // ---- issue prefetch for tile it+2 (consumed next iteration) ----
    if (it + 2 < ntiles) {
      const int nn0 = (b + (it + 2) * GRID) * BN;
      pf0a = pf0b = pf1a = pf1b = make_float4(0.f, 0.f, 0.f, 0.f);
      if (nn0 + srow0 < NB) {
        const float4* p = (const float4*)(features + (size_t)(nn0 + srow0) * KD + sck * 8);
        pf0a = p[0]; pf0b = p[1];
      }
      if (nn0 + srow1 < NB) {
        const float4* p = (const float4*)(features + (size_t)(nn0 + srow1) * KD + sck * 8);
        pf1a = p[0]; pf1b = p[1];
      }
    }

    // ---- MFMA (operand-swapped) from buf[cb]: 4 n-subtiles, K=256 ----
    floatx4 acc[4];
    #pragma unroll
    for (int nt = 0; nt < 4; ++nt) acc[nt] = floatx4{0.f, 0.f, 0.f, 0.f};

    #pragma unroll
    for (int t = 0; t < 8; ++t) {
      #pragma unroll
      for (int nt = 0; nt < 4; ++nt) {
        FragCast fc;
        fc.u = lds[cb][nt * 16 + l16][(t * 4 + quad) ^ e3];
        acc[nt] = __builtin_amdgcn_mfma_f32_16x16x32_bf16(fc.f, afrag[t], acc[nt], 0, 0, 0);
      }
    }

    // ---- store: one float4 (4 consecutive n) per n-subtile ----
    #pragma unroll
    for (int nt = 0; nt < 4; ++nt) {
      const int n = n0 + nt * 16 + q4;
      if (n < NB)    // NB%4==0 so the float4 is all-in or all-out
        *(floatx4*)(orow + n) = acc[nt];
    }
  }
}

extern "C" void kernel_launch(void* const* d_in, const int* in_sizes, int n_in,
                              void* d_out, int out_size, void* d_ws, size_t ws_size,
                              hipStream_t stream) {
  const float* inputs   = (const float*)d_in[0];  // [256,256] f32
  // d_in[1] = indexes (unused), d_in[3] = momentum (unused)
  const float* features = (const float*)d_in[2];  // [100000,256] f32
  float* out = (float*)d_out;                     // [256,100000] f32

  sct_gemm<<<GRID, 1024, 0, stream>>>(inputs, features, out);
}